// Round 10
// baseline (320.991 us; speedup 1.0000x reference)
//
#include <hip/hip_runtime.h>
#include <hip/hip_bf16.h>

#define CC 96

typedef short short8  __attribute__((ext_vector_type(8)));
typedef short short4v __attribute__((ext_vector_type(4)));
typedef float f32x4   __attribute__((ext_vector_type(4)));
typedef _Float16 half4 __attribute__((ext_vector_type(4)));

#if __has_builtin(__builtin_amdgcn_mfma_f32_16x16x16_f16)
  #define MFMA16(a,b,c) __builtin_amdgcn_mfma_f32_16x16x16_f16((a),(b),(c),0,0,0)
#else
  #define MFMA16(a,b,c) __builtin_amdgcn_mfma_f32_16x16x16f16((a),(b),(c),0,0,0)
#endif

static __device__ __forceinline__ ushort f2bf(float f) {
  __hip_bfloat16 h = __float2bfloat16(f);
  return *reinterpret_cast<ushort*>(&h);
}
static __device__ __forceinline__ float bf2f(ushort u) {
  union { unsigned int u; float f; } v; v.u = ((unsigned int)u) << 16; return v.f;
}

#define QSCALE 0.20412414523193154f

// ---------------- prep: pack all weights ----------------
__global__ void prep_kernel(const float* __restrict__ qkv_w,
                            const float* __restrict__ qkv_b,
                            const float* __restrict__ proj_w,
                            const float* __restrict__ w2w,
                            const float* __restrict__ w1w,
                            __hip_bfloat16* __restrict__ qkvp,
                            float* __restrict__ qkvb2,
                            __hip_bfloat16* __restrict__ projp,
                            __hip_bfloat16* __restrict__ w2p,
                            __hip_bfloat16* __restrict__ w1p)
{
  const int i = blockIdx.x*256 + threadIdx.x;
  if (i < 36864) {
    const int e = i & 7, lane = (i >> 3) & 63;
    const int rest = i >> 9;           // (h*3+ks)*6+mt
    const int mt = rest % 6, r2 = rest / 6;
    const int ks = r2 % 3, h = r2 / 3;
    const int od = mt*16 + (lane & 15);
    const int sec = od >> 5, d = od & 31;
    const int c = ks*32 + (lane >> 4)*8 + e;
    float val = 0.f;
    if (d < 24) {
      val = qkv_w[(sec*96 + h*24 + d)*96 + c];
      if (sec == 0) val *= QSCALE;
    }
    qkvp[i] = __float2bfloat16(val);
  }
  const int jb = i - 36864;
  if (jb >= 0 && jb < 384) {
    const int h = jb / 96, od = jb - h*96;
    const int sec = od >> 5, d = od & 31;
    float val = 0.f;
    if (d < 24) {
      val = qkv_b[sec*96 + h*24 + d];
      if (sec == 0) val *= QSCALE;
    }
    qkvb2[jb] = val;
  }
  const int j = i - 37248;
  if (j >= 0 && j < 9216) {
    const int e = j & 7, lane = (j >> 3) & 63;
    const int rest = j >> 9;           // ks*6+nt
    const int nt = rest % 6, ks = rest / 6;
    const int oc = nt*16 + (lane & 15);
    const int dd = ks*32 + (lane >> 4)*8 + e;
    projp[j] = __float2bfloat16(proj_w[oc*96 + dd]);
  }
  const int k = i - 46464;
  if (k >= 0 && k < 82944) {
    const int e = k & 7;
    const int lane = (k >> 3) & 63;
    const int rest = k >> 9;           // (tap*3+kc)*6+nf
    const int nf = rest % 6;
    const int r2 = rest / 6;
    const int kc = r2 % 3;
    const int tap = r2 / 3;
    const int cidx = kc*32 + (lane >> 4)*8 + e;
    const int oc = nf*16 + (lane & 15);
    const int ky = tap / 3, kx = tap - ky*3;
    w2p[k] = __float2bfloat16(w2w[((oc*96 + cidx)*3 + ky)*3 + kx]);
  }
  const int m = i - 129408;
  if (m >= 0 && m < 18432) {
    const int e = m & 7, lane = (m >> 3) & 63;
    const int rest = m >> 9;           // ks*12+nt
    const int nt = rest % 12, ks = rest / 12;
    const int oc = nt*16 + (lane & 15);
    const int c  = ks*32 + (lane >> 4)*8 + e;
    w1p[m] = __float2bfloat16(w1w[oc*96 + c]);
  }
}

// ---------------- Kernel 1: fused MHA + residual + RMSNorm + conv1x1 + GLU ----------------
// 2 windows/block, 512 thr = 8 waves, wave W=(w2,h). LDS 62.3KB, 2 blocks/CU.
// Raw x stays in registers from P1 to the residual epilogue (no second x fetch).
__global__ __launch_bounds__(512, 2) void attn_kernel(
    const float* __restrict__ x,
    const float* __restrict__ norm_w,
    const __hip_bfloat16* __restrict__ qkvp,
    const float* __restrict__ qkvb2,
    const __hip_bfloat16* __restrict__ projp,
    const float* __restrict__ proj_b,
    const float* __restrict__ bias_table,
    const float* __restrict__ mlp_norm_w,
    const __hip_bfloat16* __restrict__ w1p,
    const float* __restrict__ w1_b,
    float* __restrict__ out,
    __hip_bfloat16* __restrict__ y)
{
  extern __shared__ char smem[];
  ushort* xn   = (ushort*)smem;              // [128][104] bf16: xn -> o -> proj-out -> glu
  float*  btab = (float*)(smem + 61440);     // [225]

  const int wp = blockIdx.x;                 // window pair
  const int b   = wp >> 9;
  const int wy  = (wp >> 4) & 31;
  const int wxp = wp & 15;
  const int t  = threadIdx.x;
  const int y0 = wy*8, x0 = wxp*16;
  const int l  = t & 63;
  const int W  = __builtin_amdgcn_readfirstlane(t >> 6);
  const int w2 = W >> 2, h = W & 3;
  const int lr = l & 15, g = l >> 4;

  _Float16* Vt = (_Float16*)(smem + 26624 + W*4352);   // [32 d][68 tok-pad] f16

  for (int i = t; i < 225; i += 512) btab[i] = bias_table[i];

  // pixel<->thread map shared by P1 and the epilogue
  const int pp = t >> 2, qq = t & 3;
  const int pty = pp >> 4, ptx = pp & 15;
  const int prow = (ptx >> 3)*64 + pty*8 + (ptx & 7);

  // ---- P1: load x (keep raw in regs) + RMSNorm -> xn bf16 ----
  float xv[24];
  {
    const float* xp = x + (size_t)(b*CC + qq*24)*65536 + (size_t)(y0+pty)*256 + x0 + ptx;
    float ss = 0.f;
    #pragma unroll
    for (int i = 0; i < 24; i++) { xv[i] = xp[(size_t)i*65536]; ss += xv[i]*xv[i]; }
    ss += __shfl_xor(ss, 1);
    ss += __shfl_xor(ss, 2);
    const float s = rsqrtf(ss * (1.f/96.f) + 1e-6f);
    #pragma unroll
    for (int k2 = 0; k2 < 3; k2++) {
      short8 pk;
      #pragma unroll
      for (int q2 = 0; q2 < 8; q2++)
        pk[q2] = (short)f2bf(xv[k2*8+q2] * s * norm_w[qq*24 + k2*8 + q2]);
      *(short8*)(xn + prow*104 + qq*24 + k2*8) = pk;
    }
  }
  __syncthreads();   // (A)

  // ---- P2: transposed QKV GEMM in 3 low-pressure passes ----
  half4 qf[2][4], kf[2][4];
  #pragma unroll
  for (int pass = 0; pass < 2; pass++) {     // 0 -> Q, 1 -> K
    f32x4 acc[2][4];
    #pragma unroll
    for (int m2 = 0; m2 < 2; m2++)
      #pragma unroll
      for (int nt = 0; nt < 4; nt++) acc[m2][nt] = (f32x4)0.f;
    #pragma unroll
    for (int ks = 0; ks < 3; ks++) {
      short8 bfr[4];
      #pragma unroll
      for (int nt = 0; nt < 4; nt++)
        bfr[nt] = *(const short8*)((const char*)xn + (w2*64 + nt*16 + lr)*208 + g*16 + ks*64);
      #pragma unroll
      for (int m2 = 0; m2 < 2; m2++) {
        const short8 afr = *(const short8*)(qkvp + ((h*3+ks)*6 + pass*2 + m2)*512 + l*8);
        #pragma unroll
        for (int nt = 0; nt < 4; nt++)
          acc[m2][nt] = __builtin_amdgcn_mfma_f32_16x16x32_bf16(afr, bfr[nt], acc[m2][nt], 0, 0, 0);
      }
    }
    #pragma unroll
    for (int m2 = 0; m2 < 2; m2++) {
      const f32x4 bb = *(const f32x4*)(qkvb2 + h*96 + (pass*2+m2)*16 + g*4);
      #pragma unroll
      for (int nt = 0; nt < 4; nt++)
        #pragma unroll
        for (int r = 0; r < 4; r++) {
          const float v = acc[m2][nt][r] + bb[r];
          if (pass == 0) qf[m2][nt][r] = (_Float16)v;
          else           kf[m2][nt][r] = (_Float16)v;
        }
    }
  }
  {  // V pass -> Vt LDS (f16, transposed [d][tok])
    f32x4 acc[2][4];
    #pragma unroll
    for (int m2 = 0; m2 < 2; m2++)
      #pragma unroll
      for (int nt = 0; nt < 4; nt++) acc[m2][nt] = (f32x4)0.f;
    #pragma unroll
    for (int ks = 0; ks < 3; ks++) {
      short8 bfr[4];
      #pragma unroll
      for (int nt = 0; nt < 4; nt++)
        bfr[nt] = *(const short8*)((const char*)xn + (w2*64 + nt*16 + lr)*208 + g*16 + ks*64);
      #pragma unroll
      for (int m2 = 0; m2 < 2; m2++) {
        const short8 afr = *(const short8*)(qkvp + ((h*3+ks)*6 + 4 + m2)*512 + l*8);
        #pragma unroll
        for (int nt = 0; nt < 4; nt++)
          acc[m2][nt] = __builtin_amdgcn_mfma_f32_16x16x32_bf16(afr, bfr[nt], acc[m2][nt], 0, 0, 0);
      }
    }
    #pragma unroll
    for (int m2 = 0; m2 < 2; m2++) {
      const f32x4 bb = *(const f32x4*)(qkvb2 + h*96 + 64 + m2*16 + g*4);
      #pragma unroll
      for (int nt = 0; nt < 4; nt++)
        #pragma unroll
        for (int r = 0; r < 4; r++)
          Vt[(m2*16 + g*4 + r)*68 + nt*16 + lr] = (_Float16)(acc[m2][nt][r] + bb[r]);
    }
  }

  // ---- P3+P4 fused per qt: scores + softmax -> pa ----
  half4 pa[4][4];   // [kt][qt]
  #pragma unroll
  for (int qt = 0; qt < 4; qt++) {
    f32x4 sacc[4];
    #pragma unroll
    for (int kt = 0; kt < 4; kt++) {
      f32x4 s0 = MFMA16(kf[0][kt], qf[0][qt], (f32x4)0.f);
      sacc[kt] = MFMA16(kf[1][kt], qf[1][qt], s0);
    }
    const int q = qt*16 + lr;
    const int aq = (q >> 3)*15 + (q & 7);
    float vv[4][4];
    float mx = -1e30f;
    #pragma unroll
    for (int kt = 0; kt < 4; kt++)
      #pragma unroll
      for (int r = 0; r < 4; r++) {
        const int k = kt*16 + g*4 + r;
        vv[kt][r] = sacc[kt][r] + btab[aq + 112 - ((k >> 3)*15 + (k & 7))];
        mx = fmaxf(mx, vv[kt][r]);
      }
    mx = fmaxf(mx, __shfl_xor(mx, 16));
    mx = fmaxf(mx, __shfl_xor(mx, 32));
    float sum = 0.f;
    #pragma unroll
    for (int kt = 0; kt < 4; kt++)
      #pragma unroll
      for (int r = 0; r < 4; r++) { vv[kt][r] = __expf(vv[kt][r] - mx); sum += vv[kt][r]; }
    sum += __shfl_xor(sum, 16);
    sum += __shfl_xor(sum, 32);
    const float rinv = 1.f / sum;
    #pragma unroll
    for (int kt = 0; kt < 4; kt++)
      #pragma unroll
      for (int r = 0; r < 4; r++) pa[kt][qt][r] = (_Float16)(vv[kt][r] * rinv);
  }

  // ---- P5: PV in-register ----
  f32x4 oacc[4][2];
  #pragma unroll
  for (int qt = 0; qt < 4; qt++) { oacc[qt][0] = (f32x4)0.f; oacc[qt][1] = (f32x4)0.f; }
  #pragma unroll
  for (int kt = 0; kt < 4; kt++) {
    const half4 vb0 = *(const half4*)(Vt + lr*68      + kt*16 + g*4);
    const half4 vb1 = *(const half4*)(Vt + (lr+16)*68 + kt*16 + g*4);
    #pragma unroll
    for (int qt = 0; qt < 4; qt++) {
      oacc[qt][0] = MFMA16(pa[kt][qt], vb0, oacc[qt][0]);
      oacc[qt][1] = MFMA16(pa[kt][qt], vb1, oacc[qt][1]);
    }
  }
  __syncthreads();   // (B) xn reads done; o may overwrite

  #pragma unroll
  for (int qt = 0; qt < 4; qt++)
    #pragma unroll
    for (int r = 0; r < 4; r++) {
      const int row = w2*64 + qt*16 + g*4 + r;
      xn[row*104 + h*24 + lr] = f2bf(oacc[qt][0][r]);
      if (lr < 8) xn[row*104 + h*24 + 16 + lr] = f2bf(oacc[qt][1][r]);
    }
  __syncthreads();   // (C) o complete

  // ---- P6: proj (wave W owns rows W*16..W*16+15); write row-major to xn ----
  {
    f32x4 pacc[6];
    #pragma unroll
    for (int nt = 0; nt < 6; nt++) pacc[nt] = (f32x4)0.f;
    #pragma unroll
    for (int ks = 0; ks < 3; ks++) {
      const short8 af = *(const short8*)((const char*)xn + (lr + W*16)*208 + g*16 + ks*64);
      #pragma unroll
      for (int nt = 0; nt < 6; nt++) {
        const short8 bf = *(const short8*)(projp + (ks*6+nt)*512 + l*8);
        pacc[nt] = __builtin_amdgcn_mfma_f32_16x16x32_bf16(af, bf, pacc[nt], 0, 0, 0);
      }
    }
    // own rows read, own rows written -> no barrier needed in between
    #pragma unroll
    for (int nt = 0; nt < 6; nt++) {
      const int oc = lr + nt*16;
      const float bias = proj_b[oc];
      #pragma unroll
      for (int r = 0; r < 4; r++) {
        const int row = W*16 + g*4 + r;
        xn[row*104 + oc] = f2bf(pacc[nt][r] + bias);
      }
    }
  }
  __syncthreads();   // (E) proj-out complete

  // ---- P7 epilogue: out = x + attn (x in regs); then mlp RMSNorm -> xn ----
  {
    float ov[24];
    #pragma unroll
    for (int k2 = 0; k2 < 3; k2++) {
      const short8 raw = *(const short8*)(xn + prow*104 + qq*24 + k2*8);
      #pragma unroll
      for (int q2 = 0; q2 < 8; q2++) ov[k2*8+q2] = bf2f((ushort)raw[q2]);
    }
    float* op = out + (size_t)(b*CC + qq*24)*65536 + (size_t)(y0+pty)*256 + x0 + ptx;
    float ss = 0.f;
    #pragma unroll
    for (int i = 0; i < 24; i++) {
      const float v = xv[i] + ov[i];
      ov[i] = v;
      op[(size_t)i*65536] = v;
      ss += v*v;
    }
    ss += __shfl_xor(ss, 1);
    ss += __shfl_xor(ss, 2);
    const float s = rsqrtf(ss*(1.f/96.f) + 1e-6f);
    #pragma unroll
    for (int k2 = 0; k2 < 3; k2++) {
      short8 pk;
      #pragma unroll
      for (int q2 = 0; q2 < 8; q2++)
        pk[q2] = (short)f2bf(ov[k2*8+q2] * s * mlp_norm_w[qq*24 + k2*8 + q2]);
      *(short8*)(xn + prow*104 + qq*24 + k2*8) = pk;
    }
  }
  __syncthreads();   // (F) normalized tile complete

  // ---- P8: conv1x1 GEMM [128x96]@[96x192] + GLU -> xn own rows ----
  {
    f32x4 macc[12];
    #pragma unroll
    for (int nt = 0; nt < 12; nt++) macc[nt] = (f32x4)0.f;
    #pragma unroll
    for (int ks = 0; ks < 3; ks++) {
      const short8 afr = *(const short8*)((const char*)xn + (lr + W*16)*208 + g*16 + ks*64);
      #pragma unroll
      for (int nt = 0; nt < 12; nt++) {
        const short8 bfr = *(const short8*)(w1p + ((ks*12+nt)*64 + l)*8);
        macc[nt] = __builtin_amdgcn_mfma_f32_16x16x32_bf16(afr, bfr, macc[nt], 0, 0, 0);
      }
    }
    #pragma unroll
    for (int nt = 0; nt < 6; nt++) {
      const int oc = nt*16 + lr;
      const float ab = w1_b[oc], gb = w1_b[96+oc];
      #pragma unroll
      for (int r = 0; r < 4; r++) {
        const int row = W*16 + g*4 + r;
        const float a  = macc[nt][r]   + ab;
        const float gg = macc[nt+6][r] + gb;
        xn[row*104 + oc] = f2bf(a / (1.f + __expf(-gg)));
      }
    }
  }
  __syncthreads();   // (G) glu tile complete

  // ---- P9: coalesced y stores ----
  #pragma unroll
  for (int k2 = 0; k2 < 3; k2++) {
    const int e = t + k2*512;
    const int m = e / 12, ch = e - m*12;
    const int gy = y0 + ((m & 63) >> 3);
    const int gx = x0 + (m >> 6)*8 + (m & 7);
    const short8 v = *(const short8*)(&xn[m*104 + ch*8]);
    *(short8*)((ushort*)y + ((size_t)(b*65536 + gy*256 + gx))*96 + ch*8) = v;
  }
}

// ---------------- Kernel 3: conv3x3 via MFMA implicit GEMM + leaky + residual ----------------
__global__ __launch_bounds__(256) void conv3_kernel(
    const __hip_bfloat16* __restrict__ y,    // [b][hw][96]
    const __hip_bfloat16* __restrict__ w2p,
    const float* __restrict__ w2_b,
    float* __restrict__ xout)
{
  extern __shared__ char smem[];
  ushort* A = (ushort*)smem;
  float*  O = (float*)smem;

  const int bid = blockIdx.x;
  const int b   = bid >> 9;
  const int rp  = (bid >> 2) & 127;
  const int ch  = bid & 3;
  const int px0 = ch << 6;
  const int t   = threadIdx.x;
  const int w   = __builtin_amdgcn_readfirstlane(t >> 6);
  const int l   = t & 63;
  const int m15 = l & 15, lh = l >> 4;

  for (int e = t; e < 3168; e += 256) {
    const int seg  = e / 12;
    const int part = e - seg*12;
    const int ky = seg / 66;
    const int px = seg - ky*66;
    const int gy = min(255, max(0, 2*rp + ky - 1));
    const int gx = min(255, max(0, px0 + px - 1));
    const short8 v = *(const short8*)(y + ((size_t)(b*65536 + gy*256 + gx))*96 + part*8);
    *(short8*)(A + seg*104 + part*8) = v;
  }
  __syncthreads();

  f32x4 acc0[6], acc1[6];
  #pragma unroll
  for (int nf = 0; nf < 6; ++nf) { acc0[nf] = (f32x4)0.f; acc1[nf] = (f32x4)0.f; }

  for (int tap = 0; tap < 9; ++tap) {
    const int ky = tap / 3, kx = tap - ky*3;
    for (int kc = 0; kc < 3; ++kc) {
      const int cb = kc*32 + lh*8;
      const short8 a0 = *(const short8*)(A + ((ky  )*66 + 16*w + m15 + kx)*104 + cb);
      const short8 a1 = *(const short8*)(A + ((ky+1)*66 + 16*w + m15 + kx)*104 + cb);
      const short8* bp = (const short8*)w2p + ((size_t)(tap*3 + kc)*6)*64 + l;
      #pragma unroll
      for (int nf = 0; nf < 6; ++nf) {
        const short8 bf = bp[nf*64];
        acc0[nf] = __builtin_amdgcn_mfma_f32_16x16x32_bf16(a0, bf, acc0[nf], 0, 0, 0);
        acc1[nf] = __builtin_amdgcn_mfma_f32_16x16x32_bf16(a1, bf, acc1[nf], 0, 0, 0);
      }
    }
  }
  __syncthreads();

  {
    const int jb = 16*w + lh*4;
    #pragma unroll
    for (int nf = 0; nf < 6; ++nf) {
      const int oc = nf*16 + m15;
      *(f32x4*)(O + oc*132 + jb)      = acc0[nf];
      *(f32x4*)(O + oc*132 + 64 + jb) = acc1[nf];
    }
  }
  __syncthreads();

  for (int e = t; e < 3072; e += 256) {
    const int oc = e >> 5;
    const int j  = (e & 31) * 4;
    f32x4 v = *(const f32x4*)(O + oc*132 + j);
    const float bb = w2_b[oc];
    const int gy = 2*rp + (j >> 6);
    const int px = px0 + (j & 63);
    float* op = xout + ((size_t)(b*CC + oc))*65536 + (size_t)gy*256 + px;
    f32x4 r = *(const f32x4*)op;
    #pragma unroll
    for (int q = 0; q < 4; ++q) {
      float u = v[q] + bb;
      u = (u >= 0.f) ? u : 0.1f*u;
      r[q] += u;
    }
    *(f32x4*)op = r;
  }
}

extern "C" void kernel_launch(void* const* d_in, const int* in_sizes, int n_in,
                              void* d_out, int out_size, void* d_ws, size_t ws_size,
                              hipStream_t stream)
{
  (void)in_sizes; (void)n_in; (void)out_size; (void)ws_size;
  const float* x      = (const float*)d_in[0];
  const float* norm_w = (const float*)d_in[1];
  const float* qkv_w  = (const float*)d_in[2];
  const float* qkv_b  = (const float*)d_in[3];
  const float* proj_w = (const float*)d_in[4];
  const float* proj_b = (const float*)d_in[5];
  const float* btab   = (const float*)d_in[6];
  const float* mlpnw  = (const float*)d_in[7];
  const float* w1w    = (const float*)d_in[8];
  const float* w1b    = (const float*)d_in[9];
  const float* w2w    = (const float*)d_in[10];
  const float* w2b    = (const float*)d_in[11];
  float* out = (float*)d_out;

  char* ws = (char*)d_ws;
  __hip_bfloat16* y     = (__hip_bfloat16*)ws;                    // 50,331,648 B
  __hip_bfloat16* w2p   = (__hip_bfloat16*)(ws + 50331648);       // 165,888 B
  __hip_bfloat16* qkvp  = (__hip_bfloat16*)(ws + 50497536);       // 73,728 B
  float*          qkvb2 = (float*)(ws + 50571264);                // 1,536 B
  __hip_bfloat16* projp = (__hip_bfloat16*)(ws + 50572800);       // 18,432 B
  __hip_bfloat16* w1p   = (__hip_bfloat16*)(ws + 50591232);       // 36,864 B

  prep_kernel<<<578, 256, 0, stream>>>(qkv_w, qkv_b, proj_w, w2w, w1w,
                                       qkvp, qkvb2, projp, w2p, w1p);

  attn_kernel<<<2048, 512, 62340, stream>>>(x, norm_w, qkvp, qkvb2, projp, proj_b, btab,
                                            mlpnw, w1p, w1b, out, y);
  conv3_kernel<<<2048, 256, 54912, stream>>>(y, w2p, w2b, out);
}